// Round 11
// baseline (649.655 us; speedup 1.0000x reference)
//
#include <hip/hip_runtime.h>
#include <hip/hip_bf16.h>

#define D 128
#define BR 64     // rows per block (64-row tiles -> 50.4KB LDS -> 3 blocks/CU)
#define PWS 132   // Ws pitch (float4-aligned reads, staging writes conflict-free)
#define PXS 65    // Xs pitch (row-major activations; odd pitch -> conflict-free)

// ---------------------------------------------------------------------------
// CSR build: deg count -> exclusive scan -> fill   (unchanged from baseline)
// ---------------------------------------------------------------------------
__global__ void count_deg(const int* __restrict__ ei, int* __restrict__ deg, int E) {
    int e = blockIdx.x * 256 + threadIdx.x;
    if (e < E) atomicAdd(&deg[ei[E + e]], 1);
}

__global__ __launch_bounds__(256) void scan_kernel(const int* __restrict__ deg,
                                                   int* __restrict__ rowstart,
                                                   int* __restrict__ cursor, int n) {
    __shared__ int tsum[257];
    int tid = threadIdx.x;
    int chunk = (n + 255) / 256;
    int lo = tid * chunk;
    int hi = lo + chunk; if (hi > n) hi = n;
    int s = 0;
    for (int i = lo; i < hi; ++i) s += deg[i];
    tsum[tid] = s;
    __syncthreads();
    if (tid == 0) {
        int run = 0;
        for (int i = 0; i < 256; ++i) { int t = tsum[i]; tsum[i] = run; run += t; }
        tsum[256] = run;
    }
    __syncthreads();
    int run = tsum[tid];
    for (int i = lo; i < hi; ++i) {
        rowstart[i] = run; cursor[i] = run; run += deg[i];
    }
    if (tid == 0) rowstart[n] = tsum[256];
}

__global__ void fill_csr(const int* __restrict__ ei, int* __restrict__ cursor,
                         int* __restrict__ csr, int E) {
    int e = blockIdx.x * 256 + threadIdx.x;
    if (e < E) {
        int s = ei[e];
        int d = ei[E + e];
        int p = atomicAdd(&cursor[d], 1);
        csr[p] = s;
    }
}

// ---------------------------------------------------------------------------
// GEMM1: m_nodes = x @ W_msg + b_msg.  64-row tile, K-chunks of 64.
// Thread map: tr = tid>>5 (8 row-groups x 8 rows), tc = tid&31 (32 col-groups x 4).
// ---------------------------------------------------------------------------
__global__ __launch_bounds__(256, 3) void gemm_msg(const float* __restrict__ x,
                                                   const float* __restrict__ W,
                                                   const float* __restrict__ b,
                                                   float* __restrict__ out, int n) {
    __shared__ __align__(16) float Ws[64 * PWS];
    __shared__ __align__(16) float Xs[BR * PXS];
    const int tid = threadIdx.x;
    const int R0 = blockIdx.x * BR;
    const int tr = tid >> 5, tc = tid & 31;
    const int r0 = tr * 8, c0 = tc * 4;

    float acc[8][4];
#pragma unroll
    for (int i = 0; i < 8; ++i)
#pragma unroll
        for (int j = 0; j < 4; ++j) acc[i][j] = 0.f;

    for (int ch = 0; ch < 2; ++ch) {
        const int k0 = ch * 64;
        if (ch) __syncthreads();
        // stage W rows [k0,k0+64) x 128 cols (coalesced read, conflict-free write)
        for (int t = 0; t < 32; ++t) {
            int e = t * 256 + tid;
            int k = e >> 7, c = e & 127;
            Ws[k * PWS + c] = W[(k0 + k) * D + c];
        }
        // stage x rows [R0,R0+64) cols [k0,k0+64) row-major (coalesced, 2-way)
        for (int t = 0; t < 16; ++t) {
            int e = t * 256 + tid;
            int r = e >> 6, c = e & 63;
            int gr = R0 + r; if (gr >= n) gr = n - 1;
            Xs[r * PXS + c] = x[(long)gr * D + k0 + c];
        }
        __syncthreads();
        for (int k = 0; k < 64; ++k) {
            float4 wa = *(const float4*)&Ws[k * PWS + c0];
            float xs[8];
#pragma unroll
            for (int i = 0; i < 8; ++i) xs[i] = Xs[(r0 + i) * PXS + k];
#pragma unroll
            for (int i = 0; i < 8; ++i) {
                acc[i][0] += xs[i] * wa.x; acc[i][1] += xs[i] * wa.y;
                acc[i][2] += xs[i] * wa.z; acc[i][3] += xs[i] * wa.w;
            }
        }
    }

    const float4 bj = *(const float4*)&b[c0];
#pragma unroll
    for (int i = 0; i < 8; ++i) {
        int row = R0 + r0 + i;
        if (row < n) {
            float4 o;
            o.x = acc[i][0] + bj.x; o.y = acc[i][1] + bj.y;
            o.z = acc[i][2] + bj.z; o.w = acc[i][3] + bj.w;
            *(float4*)&out[(long)row * D + c0] = o;
        }
    }
}

// ---------------------------------------------------------------------------
// aggr[n] = sum over incoming edges of m_nodes[src].  (unchanged from baseline)
// ---------------------------------------------------------------------------
__global__ __launch_bounds__(256) void aggr_kernel(const float* __restrict__ mn,
                                                   const int* __restrict__ rowstart,
                                                   const int* __restrict__ csr,
                                                   float* __restrict__ aggr, int n) {
    int gw = (blockIdx.x * 256 + threadIdx.x) >> 6;
    int lane = threadIdx.x & 63;
    if (gw >= n) return;
    int rs = rowstart[gw], re = rowstart[gw + 1];
    float ax = 0.f, ay = 0.f, bx = 0.f, by = 0.f;
    int i = rs;
    for (; i + 1 < re; i += 2) {
        int s0 = csr[i], s1 = csr[i + 1];
        float2 v0 = *(const float2*)&mn[(long)s0 * D + lane * 2];
        float2 v1 = *(const float2*)&mn[(long)s1 * D + lane * 2];
        ax += v0.x; ay += v0.y; bx += v1.x; by += v1.y;
    }
    if (i < re) {
        int s0 = csr[i];
        float2 v0 = *(const float2*)&mn[(long)s0 * D + lane * 2];
        ax += v0.x; ay += v0.y;
    }
    float2 o; o.x = ax + bx; o.y = ay + by;
    *(float2*)&aggr[(long)gw * D + lane * 2] = o;
}

// ---------------------------------------------------------------------------
// Fused update, 64-row tiles, K-chunks of 64:
//   conv_out = [x, aggr] @ W_upd + b_upd          (4 chunks: 2 x-src, 2 aggr-src)
//   gate     = sigmoid([conv_out, imp] @ W_gate + b_gate)   (2 chunks, conv^T
//              restaged into Xs from registers)
//   out      = gate*conv_out + (1-gate)*x
//   p_imp    = out @ W_imp + b_imp                (width-32 shfl reduce)
// ---------------------------------------------------------------------------
__global__ __launch_bounds__(256, 3) void fused_update(
        const float* __restrict__ x, const float* __restrict__ aggr,
        const float* __restrict__ imp,
        const float* __restrict__ W_upd, const float* __restrict__ b_upd,
        const float* __restrict__ W_gate, const float* __restrict__ b_gate,
        const float* __restrict__ W_imp, const float* __restrict__ b_imp,
        float* __restrict__ out, int n) {
    __shared__ __align__(16) float Ws[64 * PWS];
    __shared__ __align__(16) float Xs[BR * PXS];
    const int tid = threadIdx.x;
    const int R0 = blockIdx.x * BR;
    const int tr = tid >> 5, tc = tid & 31;
    const int r0 = tr * 8, c0 = tc * 4;

    float acc[8][4];
#pragma unroll
    for (int i = 0; i < 8; ++i)
#pragma unroll
        for (int j = 0; j < 4; ++j) acc[i][j] = 0.f;

    // ---- update GEMM: 4 K-chunks over [x | aggr] ----
    for (int ch = 0; ch < 4; ++ch) {
        const int k0 = ch * 64;                 // row offset into W_upd
        const float* src = (ch < 2) ? x : aggr;
        const int koff = (ch & 1) * 64;         // col offset into src
        if (ch) __syncthreads();
        for (int t = 0; t < 32; ++t) {
            int e = t * 256 + tid;
            int k = e >> 7, c = e & 127;
            Ws[k * PWS + c] = W_upd[(k0 + k) * D + c];
        }
        for (int t = 0; t < 16; ++t) {
            int e = t * 256 + tid;
            int r = e >> 6, c = e & 63;
            int gr = R0 + r; if (gr >= n) gr = n - 1;
            Xs[r * PXS + c] = src[(long)gr * D + koff + c];
        }
        __syncthreads();
        for (int k = 0; k < 64; ++k) {
            float4 wa = *(const float4*)&Ws[k * PWS + c0];
            float xs[8];
#pragma unroll
            for (int i = 0; i < 8; ++i) xs[i] = Xs[(r0 + i) * PXS + k];
#pragma unroll
            for (int i = 0; i < 8; ++i) {
                acc[i][0] += xs[i] * wa.x; acc[i][1] += xs[i] * wa.y;
                acc[i][2] += xs[i] * wa.z; acc[i][3] += xs[i] * wa.w;
            }
        }
    }

    // ---- bias: acc now holds conv_out for rows r0.. x cols c0.. ----
    {
        const float4 bu = *(const float4*)&b_upd[c0];
#pragma unroll
        for (int i = 0; i < 8; ++i) {
            acc[i][0] += bu.x; acc[i][1] += bu.y;
            acc[i][2] += bu.z; acc[i][3] += bu.w;
        }
    }

    // ---- gate GEMM: 2 K-chunks, conv_out restaged from registers ----
    float g[8][4];
#pragma unroll
    for (int i = 0; i < 8; ++i)
#pragma unroll
        for (int j = 0; j < 4; ++j) g[i][j] = 0.f;

    for (int gc = 0; gc < 2; ++gc) {
        __syncthreads();   // previous chunk fully read
        for (int t = 0; t < 32; ++t) {
            int e = t * 256 + tid;
            int k = e >> 7, c = e & 127;
            Ws[k * PWS + c] = W_gate[(gc * 64 + k) * D + c];
        }
        if ((c0 >> 6) == gc) {   // this thread's cols belong to this chunk
            const int cb = c0 & 63;
#pragma unroll
            for (int i = 0; i < 8; ++i)
#pragma unroll
                for (int j = 0; j < 4; ++j)
                    Xs[(r0 + i) * PXS + cb + j] = acc[i][j];
        }
        __syncthreads();
        for (int k = 0; k < 64; ++k) {
            float4 wa = *(const float4*)&Ws[k * PWS + c0];
            float xs[8];
#pragma unroll
            for (int i = 0; i < 8; ++i) xs[i] = Xs[(r0 + i) * PXS + k];
#pragma unroll
            for (int i = 0; i < 8; ++i) {
                g[i][0] += xs[i] * wa.x; g[i][1] += xs[i] * wa.y;
                g[i][2] += xs[i] * wa.z; g[i][3] += xs[i] * wa.w;
            }
        }
    }

    // ---- gate, mix, store out; then p_imp ----
    const float4 wgl = *(const float4*)&W_gate[128 * D + c0];  // importance row
    const float4 bg  = *(const float4*)&b_gate[c0];
    const float4 wim = *(const float4*)&W_imp[c0];
    const float bi = b_imp[0];

#pragma unroll
    for (int i = 0; i < 8; ++i) {
        int row = R0 + r0 + i;
        int crow = row < n ? row : n - 1;
        float iv = imp[crow];
        float4 xv = *(const float4*)&x[(long)crow * D + c0];
        float z0 = g[i][0] + iv * wgl.x + bg.x;
        float z1 = g[i][1] + iv * wgl.y + bg.y;
        float z2 = g[i][2] + iv * wgl.z + bg.z;
        float z3 = g[i][3] + iv * wgl.w + bg.w;
        float s0 = 1.0f / (1.0f + expf(-z0));
        float s1 = 1.0f / (1.0f + expf(-z1));
        float s2 = 1.0f / (1.0f + expf(-z2));
        float s3 = 1.0f / (1.0f + expf(-z3));
        g[i][0] = s0 * acc[i][0] + (1.0f - s0) * xv.x;
        g[i][1] = s1 * acc[i][1] + (1.0f - s1) * xv.y;
        g[i][2] = s2 * acc[i][2] + (1.0f - s2) * xv.z;
        g[i][3] = s3 * acc[i][3] + (1.0f - s3) * xv.w;
        if (row < n) {
            float4 o; o.x = g[i][0]; o.y = g[i][1]; o.z = g[i][2]; o.w = g[i][3];
            *(float4*)&out[(long)row * D + c0] = o;
        }
    }

    // p_imp: per row, dot(out_row, W_imp) reduced across the 32 col-groups
#pragma unroll
    for (int i = 0; i < 8; ++i) {
        float pi = g[i][0] * wim.x + g[i][1] * wim.y + g[i][2] * wim.z + g[i][3] * wim.w;
#pragma unroll
        for (int m = 16; m >= 1; m >>= 1) pi += __shfl_xor(pi, m, 32);
        int row = R0 + r0 + i;
        if (tc == 0 && row < n) out[(long)n * D + row] = pi + bi;
    }
}

// ---------------------------------------------------------------------------
extern "C" void kernel_launch(void* const* d_in, const int* in_sizes, int n_in,
                              void* d_out, int out_size, void* d_ws, size_t ws_size,
                              hipStream_t stream) {
    const float* x      = (const float*)d_in[0];
    const int*   ei     = (const int*)d_in[1];
    const float* imp    = (const float*)d_in[2];
    const float* W_msg  = (const float*)d_in[3];
    const float* b_msg  = (const float*)d_in[4];
    const float* W_upd  = (const float*)d_in[5];
    const float* b_upd  = (const float*)d_in[6];
    const float* W_gate = (const float*)d_in[7];
    const float* b_gate = (const float*)d_in[8];
    const float* W_imp  = (const float*)d_in[9];
    const float* b_imp  = (const float*)d_in[10];
    float* out = (float*)d_out;

    const int N = in_sizes[0] / D;
    const int E = in_sizes[1] / 2;

    char* ws = (char*)d_ws;
    float* m_nodes  = (float*)ws;  ws += (size_t)N * D * sizeof(float);
    float* aggr     = (float*)ws;  ws += (size_t)N * D * sizeof(float);
    int*   deg      = (int*)ws;    ws += (size_t)N * sizeof(int);
    int*   rowstart = (int*)ws;    ws += (size_t)(N + 1) * sizeof(int);
    int*   cursor   = (int*)ws;    ws += (size_t)N * sizeof(int);
    int*   csr      = (int*)ws;    ws += (size_t)E * sizeof(int);

    hipMemsetAsync(deg, 0, (size_t)N * sizeof(int), stream);

    count_deg<<<(E + 255) / 256, 256, 0, stream>>>(ei, deg, E);
    scan_kernel<<<1, 256, 0, stream>>>(deg, rowstart, cursor, N);
    fill_csr<<<(E + 255) / 256, 256, 0, stream>>>(ei, cursor, csr, E);

    const int nblk = (N + BR - 1) / BR;
    gemm_msg<<<nblk, 256, 0, stream>>>(x, W_msg, b_msg, m_nodes, N);

    aggr_kernel<<<((size_t)N * 64 + 255) / 256, 256, 0, stream>>>(
        m_nodes, rowstart, csr, aggr, N);

    fused_update<<<nblk, 256, 0, stream>>>(x, aggr, imp, W_upd, b_upd,
                                           W_gate, b_gate, W_imp, b_imp,
                                           out, N);
}